// Round 4
// baseline (1745.027 us; speedup 1.0000x reference)
//
#include <hip/hip_runtime.h>
#include <hip/hip_bf16.h>

#define NN 50000
#define NE 800000
#define DIMX 288

typedef float float4v __attribute__((ext_vector_type(4)));

__device__ __forceinline__ float b2f(unsigned short u) {
  return __uint_as_float(((unsigned int)u) << 16);
}
__device__ __forceinline__ unsigned short f2b(float f) {
  unsigned int x = __float_as_uint(f);
  x += 0x7fffu + ((x >> 16) & 1u);
  return (unsigned short)(x >> 16);
}
// dtype-dispatched float load: f32!=0 -> fp32 array, else bf16 array
__device__ __forceinline__ float ldf(const void* p, long i, int f32) {
  return f32 ? ((const float*)p)[i] : b2f(((const unsigned short*)p)[i]);
}
// index load: i64!=0 -> low word of int64 element, else int32 element
__device__ __forceinline__ int ldidx(const int* p, long i, int i64) {
  return i64 ? p[2 * i] : p[i];
}

// ---------------- Kernel 0: dtype detector ----------------
// flags[0]=1 iff float arrays are fp32; flags[1]=1 iff edge_index is int64.
__global__ void k_detect(const unsigned short* __restrict__ pos_u16,
                         const int* __restrict__ eidx_i32,
                         int* __restrict__ flags) {
  if (threadIdx.x == 0 && blockIdx.x == 0) {
    int insane = 0;
    for (int i = 0; i < 128; ++i) {
      unsigned short u = pos_u16[i];
      int e = (u >> 7) & 0xff;          // bf16 exponent field
      if (e >= 0xC2) insane++;          // |x| >= 2^67 (pos is in [0,10] if bf16)
    }
    flags[0] = (insane >= 2) ? 1 : 0;
    int nz = 0;
    for (int i = 1; i < 16; i += 2) nz += (eidx_i32[i] != 0);
    flags[1] = (nz == 0) ? 1 : 0;       // int64 high words are all zero
  }
}

// ---------------- Kernel 1: si1 = irreps_linear(nodes) -> bf16 ----------------
__global__ __launch_bounds__(256) void k_linear1(
    const void* __restrict__ nodes,
    const void* __restrict__ W0,
    const void* __restrict__ W1,
    const void* __restrict__ W2,
    unsigned short* __restrict__ si1,
    const int* __restrict__ flags) {
  const int f32 = flags[0];
  __shared__ float Ws[3072];       // W0|W1|W2 as fp32, row-major [i][j]
  __shared__ float xs[4 * DIMX];
  int tid = threadIdx.x;
  for (int idx = tid; idx < 3072; idx += 256) {
    int l = idx >> 10, rem = idx & 1023;
    const void* w = (l == 0) ? W0 : ((l == 1) ? W1 : W2);
    Ws[idx] = ldf(w, rem, f32);
  }
  long base = (long)blockIdx.x * 4;
  for (int idx = tid; idx < 1152; idx += 256)
    xs[idx] = ldf(nodes, base * DIMX + idx, f32);
  __syncthreads();
  int wid = tid >> 6, lane = tid & 63;
  long node = base + wid;
  const float* x = xs + wid * DIMX;
  #pragma unroll
  for (int r = 0; r < 5; ++r) {
    int j = r * 64 + lane;
    if (j < DIMX) {
      float acc = 0.f;
      if (j < 32) {
        #pragma unroll
        for (int i = 0; i < 32; ++i) acc += x[i] * Ws[i * 32 + j];
      } else if (j < 128) {
        unsigned jj = j - 32; int m = jj / 3u, c = jj % 3u;
        #pragma unroll
        for (int i = 0; i < 32; ++i) acc += x[32 + 3 * i + c] * Ws[1024 + i * 32 + m];
      } else {
        unsigned jj = j - 128; int m = jj / 5u, c = jj % 5u;
        #pragma unroll
        for (int i = 0; i < 32; ++i) acc += x[128 + 5 * i + c] * Ws[2048 + i * 32 + m];
      }
      si1[node * DIMX + j] = f2b(acc);
    }
  }
}

// ---------------- Kernel 2: zero the conv accumulator ----------------
__global__ __launch_bounds__(256) void k_zero(float* __restrict__ conv) {
  long idx = (long)blockIdx.x * 256 + threadIdx.x;
  if (idx < (long)NN * DIMX / 4) {
    float4 z; z.x = 0.f; z.y = 0.f; z.z = 0.f; z.w = 0.f;
    ((float4*)conv)[idx] = z;
  }
}

// ---------------- Kernel 3: fused edge kernel (plain VALU) ----------------
// block=256 = 4 waves; block handles 64 edges; each wave handles 16 edges.
__global__ __launch_bounds__(256) void k_edges(
    const void* __restrict__ pos,
    const int* __restrict__ eidx,
    const void* __restrict__ Wr1,
    const void* __restrict__ br1,
    const void* __restrict__ Wr2,
    const unsigned short* __restrict__ si1,
    float* __restrict__ conv,
    const int* __restrict__ flags) {
  const int f32 = flags[0];
  const int i64 = flags[1];
  __shared__ unsigned short Wr2s[64 * 228]; // bf16 [k][j], j padded 224->228
  __shared__ float wr1s[576];               // Wr1 [8][64] + br1 [64]
  __shared__ float geom[64][16];            // Y1(3) Y2(5) rbf(8)
  __shared__ unsigned int sdv[2][64];       // src, dst
  __shared__ float hbuf[4][64];             // per-wave h
  __shared__ float wev[4][224];             // per-wave w (norm folded)
  __shared__ float xsv[4][DIMX];            // per-wave gathered x
  int tid = threadIdx.x, lane = tid & 63, wid = tid >> 6;

  for (int idx = tid; idx < 512; idx += 256) wr1s[idx] = ldf(Wr1, idx, f32);
  if (tid < 64) wr1s[512 + tid] = ldf(br1, tid, f32);
  for (int idx = tid; idx < 64 * 224; idx += 256) {
    int k = idx / 224, j = idx - k * 224;
    Wr2s[k * 228 + j] = f2b(ldf(Wr2, idx, f32));
  }
  if (tid < 64) {
    long e = (long)blockIdx.x * 64 + tid;
    int s = ldidx(eidx, e, i64);
    int d = ldidx(eidx, NE + e, i64);
    sdv[0][tid] = (unsigned)s; sdv[1][tid] = (unsigned)d;
    float rx = ldf(pos, 3 * (long)s, f32)     - ldf(pos, 3 * (long)d, f32);
    float ry = ldf(pos, 3 * (long)s + 1, f32) - ldf(pos, 3 * (long)d + 1, f32);
    float rz = ldf(pos, 3 * (long)s + 2, f32) - ldf(pos, 3 * (long)d + 2, f32);
    float dd = sqrtf(rx * rx + ry * ry + rz * rz + 1e-12f);
    float inv = 1.0f / dd;
    float ux = rx * inv, uy = ry * inv, uz = rz * inv;
    geom[tid][0] = ux; geom[tid][1] = uy; geom[tid][2] = uz;
    geom[tid][3] = ux * uy;
    geom[tid][4] = uy * uz;
    geom[tid][5] = (3.f * uz * uz - 1.f) * 0.28867513459481287f;  // /(2*sqrt(3))
    geom[tid][6] = ux * uz;
    geom[tid][7] = (ux * ux - uy * uy) * 0.5f;
    #pragma unroll
    for (int k = 0; k < 8; ++k) {
      float t = dd - (float)k * (5.0f / 7.0f);
      geom[tid][8 + k] = __expf(-t * t);
    }
  }
  __syncthreads();

  #pragma unroll 1
  for (int el = 0; el < 16; ++el) {
    int eb = wid * 16 + el;
    unsigned s = sdv[0][eb];
    // --- h = silu(rbf @ Wr1 + br1): lane k computes h[k] ---
    {
      float a = wr1s[512 + lane];
      const float* rb = &geom[eb][8];
      #pragma unroll
      for (int r = 0; r < 8; ++r) a += rb[r] * wr1s[r * 64 + lane];
      hbuf[wid][lane] = a / (1.f + __expf(-a));
    }
    // --- gather x(src) from si1 (always bf16, ours) ---
    for (int i = lane; i < DIMX; i += 64) xsv[wid][i] = b2f(si1[(size_t)s * DIMX + i]);
    __syncthreads();
    // --- w = (h @ Wr2) * norm: lane handles 4 consecutive j ---
    if (lane < 56) {
      float4v acc = {0.f, 0.f, 0.f, 0.f};
      const float* hv = hbuf[wid];
      #pragma unroll 8
      for (int k = 0; k < 64; ++k) {
        float hk = hv[k];
        const unsigned short* wrow = &Wr2s[k * 228 + lane * 4];
        acc[0] += hk * b2f(wrow[0]);
        acc[1] += hk * b2f(wrow[1]);
        acc[2] += hk * b2f(wrow[2]);
        acc[3] += hk * b2f(wrow[3]);
      }
      float* wp = &wev[wid][lane * 4];
      wp[0] = acc[0] * 0.25f; wp[1] = acc[1] * 0.25f;
      wp[2] = acc[2] * 0.25f; wp[3] = acc[3] * 0.25f;
    }
    __syncthreads();
    // --- messages + atomic scatter ---
    {
      unsigned dn = sdv[1][eb];
      float* cv = conv + (size_t)dn * DIMX;
      const float* G = geom[eb];
      float y1x = G[0], y1y = G[1], y1z = G[2];
      float y20 = G[3], y21 = G[4], y22 = G[5], y23 = G[6], y24 = G[7];
      const float* X = xsv[wid];
      const float* W = wev[wid];
      #pragma unroll
      for (int r = 0; r < 5; ++r) {
        int j = r * 64 + lane;
        if (j < DIMX) {
          float val;
          if (j < 32) {
            int m = j;
            float d1 = X[32 + 3 * m] * y1x + X[33 + 3 * m] * y1y + X[34 + 3 * m] * y1z;
            float d2 = X[128 + 5 * m] * y20 + X[129 + 5 * m] * y21 + X[130 + 5 * m] * y22
                     + X[131 + 5 * m] * y23 + X[132 + 5 * m] * y24;
            val = W[m] * X[m] + W[128 + m] * d1 + W[192 + m] * d2;
          } else if (j < 128) {
            unsigned jj = j - 32; int m = jj / 3u, c = jj % 3u;
            float Yc = (c == 0) ? y1x : ((c == 1) ? y1y : y1z);
            val = W[32 + m] * X[j] + W[96 + m] * X[m] * Yc;
          } else {
            unsigned jj = j - 128; int m = jj / 5u, c = jj % 5u;
            float Yc = (c == 0) ? y20 : (c == 1) ? y21 : (c == 2) ? y22 : (c == 3) ? y23 : y24;
            val = W[64 + m] * X[j] + W[160 + m] * X[m] * Yc;
          }
          atomicAdd(cv + j, val);   // norm already folded into wev
        }
      }
    }
    __syncthreads();
  }
}

// ---------------- Kernel 4: si2 = linear(conv); mixed = nodes + si2; gate -> fp32 out ----------------
__global__ __launch_bounds__(256) void k_gate(
    const float* __restrict__ conv,
    const void* __restrict__ nodes,
    const void* __restrict__ W0,
    const void* __restrict__ W1,
    const void* __restrict__ W2,
    const void* __restrict__ Wg,
    float* __restrict__ out,
    const int* __restrict__ flags) {
  const int f32 = flags[0];
  __shared__ float Ws[3072];
  __shared__ float Wgs[2048];   // Wg [32][64]
  __shared__ float xs[4 * DIMX];
  __shared__ float m0s[4][33];
  __shared__ float gs[4][65];
  int tid = threadIdx.x;
  for (int idx = tid; idx < 3072; idx += 256) {
    int l = idx >> 10, rem = idx & 1023;
    const void* w = (l == 0) ? W0 : ((l == 1) ? W1 : W2);
    Ws[idx] = ldf(w, rem, f32);
  }
  for (int idx = tid; idx < 2048; idx += 256) Wgs[idx] = ldf(Wg, idx, f32);
  long base = (long)blockIdx.x * 4;
  for (int idx = tid; idx < 1152; idx += 256) xs[idx] = conv[base * DIMX + idx];
  __syncthreads();
  int wid = tid >> 6, lane = tid & 63;
  long node = base + wid;
  const float* x = xs + wid * DIMX;
  float mixed[5];
  #pragma unroll
  for (int r = 0; r < 5; ++r) {
    int j = r * 64 + lane;
    if (j < DIMX) {
      float acc = 0.f;
      if (j < 32) {
        #pragma unroll
        for (int i = 0; i < 32; ++i) acc += x[i] * Ws[i * 32 + j];
      } else if (j < 128) {
        unsigned jj = j - 32; int m = jj / 3u, c = jj % 3u;
        #pragma unroll
        for (int i = 0; i < 32; ++i) acc += x[32 + 3 * i + c] * Ws[1024 + i * 32 + m];
      } else {
        unsigned jj = j - 128; int m = jj / 5u, c = jj % 5u;
        #pragma unroll
        for (int i = 0; i < 32; ++i) acc += x[128 + 5 * i + c] * Ws[2048 + i * 32 + m];
      }
      acc += ldf(nodes, node * DIMX + j, f32);
      mixed[r] = acc;
      if (j < 32) m0s[wid][j] = acc;
    }
  }
  __syncthreads();
  {
    float ga = 0.f;
    #pragma unroll
    for (int m = 0; m < 32; ++m) ga += m0s[wid][m] * Wgs[m * 64 + lane];
    gs[wid][lane] = 1.f / (1.f + __expf(-ga));
  }
  __syncthreads();
  #pragma unroll
  for (int r = 0; r < 5; ++r) {
    int j = r * 64 + lane;
    if (j < DIMX) {
      float v = mixed[r];
      float o;
      if (j < 32) {
        o = v / (1.f + __expf(-v));                       // silu
      } else if (j < 128) {
        int m = (unsigned)(j - 32) / 3u; o = v * gs[wid][m];
      } else {
        int m = (unsigned)(j - 128) / 5u; o = v * gs[wid][32 + m];
      }
      out[node * DIMX + j] = o;
    }
  }
}

extern "C" void kernel_launch(void* const* d_in, const int* in_sizes, int n_in,
                              void* d_out, int out_size, void* d_ws, size_t ws_size,
                              hipStream_t stream) {
  const void* nodes = d_in[0];
  const void* pos   = d_in[1];
  const void* W0    = d_in[2];
  const void* W1    = d_in[3];
  const void* W2    = d_in[4];
  const void* Wr1   = d_in[5];
  const void* br1   = d_in[6];
  const void* Wr2   = d_in[7];
  const void* Wg    = d_in[8];
  const int* eidx   = (const int*)d_in[10];

  int* flags = (int*)d_ws;                                            // 256 B header
  unsigned short* si1 = (unsigned short*)((char*)d_ws + 256);         // 28.8 MB bf16
  float* conv = (float*)((char*)d_ws + 256 + (size_t)NN * DIMX * 2);  // 57.6 MB fp32
  float* out = (float*)d_out;

  hipLaunchKernelGGL(k_detect, dim3(1), dim3(64), 0, stream,
                     (const unsigned short*)pos, eidx, flags);
  hipLaunchKernelGGL(k_linear1, dim3(NN / 4), dim3(256), 0, stream,
                     nodes, W0, W1, W2, si1, flags);
  hipLaunchKernelGGL(k_zero, dim3((NN * DIMX / 4 + 255) / 256), dim3(256), 0, stream, conv);
  hipLaunchKernelGGL(k_edges, dim3(NE / 64), dim3(256), 0, stream,
                     pos, eidx, Wr1, br1, Wr2, si1, conv, flags);
  hipLaunchKernelGGL(k_gate, dim3(NN / 4), dim3(256), 0, stream,
                     conv, nodes, W0, W1, W2, Wg, out, flags);
}

// Round 5
// 1310.056 us; speedup vs baseline: 1.3320x; 1.3320x over previous
//
#include <hip/hip_runtime.h>
#include <hip/hip_bf16.h>

#define NN 50000
#define NE 800000
#define DIMX 288

typedef float float4v __attribute__((ext_vector_type(4)));
typedef short short8 __attribute__((ext_vector_type(8)));

__device__ __forceinline__ float b2f(unsigned short u) {
  return __uint_as_float(((unsigned int)u) << 16);
}
__device__ __forceinline__ unsigned short f2b(float f) {
  unsigned int x = __float_as_uint(f);
  x += 0x7fffu + ((x >> 16) & 1u);
  return (unsigned short)(x >> 16);
}
// dtype-dispatched float load: f32!=0 -> fp32 array, else bf16 array
__device__ __forceinline__ float ldf(const void* p, long i, int f32) {
  return f32 ? ((const float*)p)[i] : b2f(((const unsigned short*)p)[i]);
}
// index load: i64!=0 -> low word of int64 element, else int32 element
__device__ __forceinline__ int ldidx(const int* p, long i, int i64) {
  return i64 ? p[2 * i] : p[i];
}

// ---------------- Kernel 0: dtype detector ----------------
__global__ void k_detect(const unsigned short* __restrict__ pos_u16,
                         const int* __restrict__ eidx_i32,
                         int* __restrict__ flags) {
  if (threadIdx.x == 0 && blockIdx.x == 0) {
    int insane = 0;
    for (int i = 0; i < 128; ++i) {
      unsigned short u = pos_u16[i];
      int e = (u >> 7) & 0xff;          // bf16 exponent field
      if (e >= 0xC2) insane++;          // |x| >= 2^67 (pos is in [0,10] if bf16)
    }
    flags[0] = (insane >= 2) ? 1 : 0;
    int nz = 0;
    for (int i = 1; i < 16; i += 2) nz += (eidx_i32[i] != 0);
    flags[1] = (nz == 0) ? 1 : 0;       // int64 high words are all zero
  }
}

// ---------------- Kernel 1: si1 = irreps_linear(nodes) -> bf16 ----------------
__global__ __launch_bounds__(256) void k_linear1(
    const void* __restrict__ nodes,
    const void* __restrict__ W0,
    const void* __restrict__ W1,
    const void* __restrict__ W2,
    unsigned short* __restrict__ si1,
    const int* __restrict__ flags) {
  const int f32 = flags[0];
  __shared__ float Ws[3072];       // W0|W1|W2 as fp32, row-major [i][j]
  __shared__ float xs[4 * DIMX];
  int tid = threadIdx.x;
  for (int idx = tid; idx < 3072; idx += 256) {
    int l = idx >> 10, rem = idx & 1023;
    const void* w = (l == 0) ? W0 : ((l == 1) ? W1 : W2);
    Ws[idx] = ldf(w, rem, f32);
  }
  long base = (long)blockIdx.x * 4;
  for (int idx = tid; idx < 1152; idx += 256)
    xs[idx] = ldf(nodes, base * DIMX + idx, f32);
  __syncthreads();
  int wid = tid >> 6, lane = tid & 63;
  long node = base + wid;
  const float* x = xs + wid * DIMX;
  #pragma unroll
  for (int r = 0; r < 5; ++r) {
    int j = r * 64 + lane;
    if (j < DIMX) {
      float acc = 0.f;
      if (j < 32) {
        #pragma unroll
        for (int i = 0; i < 32; ++i) acc += x[i] * Ws[i * 32 + j];
      } else if (j < 128) {
        unsigned jj = j - 32; int m = jj / 3u, c = jj % 3u;
        #pragma unroll
        for (int i = 0; i < 32; ++i) acc += x[32 + 3 * i + c] * Ws[1024 + i * 32 + m];
      } else {
        unsigned jj = j - 128; int m = jj / 5u, c = jj % 5u;
        #pragma unroll
        for (int i = 0; i < 32; ++i) acc += x[128 + 5 * i + c] * Ws[2048 + i * 32 + m];
      }
      si1[node * DIMX + j] = f2b(acc);
    }
  }
}

// ---------------- Kernel 2: zero the conv accumulator ----------------
__global__ __launch_bounds__(256) void k_zero(float* __restrict__ conv) {
  long idx = (long)blockIdx.x * 256 + threadIdx.x;
  if (idx < (long)NN * DIMX / 4) {
    float4 z; z.x = 0.f; z.y = 0.f; z.z = 0.f; z.w = 0.f;
    ((float4*)conv)[idx] = z;
  }
}

// ---------------- Kernel 3: fused edge kernel (MFMA radial GEMM) ----------------
// block=256 = 4 waves; block handles 64 edges; each wave owns 16 edges.
// A-frag: A[m=lane&15][k=(lane>>4)*8+j] = h[edge m][hidden k] (bf16)
// B-frag: B[k][n=lane&15] from wr2t[j=n][k] (transposed LDS, +8 pad)
// C/D:    D[row=(lane>>4)*4+reg][col=lane&15] = w[edge row][out col]
// In-loop LDS buffers (wev, xsv) are wave-private: no __syncthreads needed
// (wave64 lockstep + in-order LDS pipeline); compiler fences only.
__global__ __launch_bounds__(256) void k_edges(
    const void* __restrict__ pos,
    const int* __restrict__ eidx,
    const void* __restrict__ Wr1,
    const void* __restrict__ br1,
    const void* __restrict__ Wr2,
    const unsigned short* __restrict__ si1,
    float* __restrict__ conv,
    const int* __restrict__ flags) {
  const int f32 = flags[0];
  const int i64 = flags[1];
  __shared__ unsigned short wr2t[224 * 72];  // [j][k] bf16, pad 64->72 (32256 B)
  __shared__ float wr1s[576];                // Wr1 [8][64] + br1 [64]
  __shared__ float geom[64][16];             // Y1(3) Y2(5) rbf(8)
  __shared__ unsigned int sdv[2][64];        // src, dst
  __shared__ float wev[4][228];              // per-wave current-edge w (norm folded)
  __shared__ float xsv[4][2][296];           // per-wave double-buffered gathered x
  int tid = threadIdx.x, lane = tid & 63, wid = tid >> 6;

  for (int idx = tid; idx < 512; idx += 256) wr1s[idx] = ldf(Wr1, idx, f32);
  if (tid < 64) wr1s[512 + tid] = ldf(br1, tid, f32);
  // stage Wr2 transposed: global reads coalesced (idx = k*224+j, j fastest)
  for (int idx = tid; idx < 64 * 224; idx += 256) {
    int k = idx / 224, j = idx - k * 224;
    wr2t[j * 72 + k] = f2b(ldf(Wr2, idx, f32));
  }
  if (tid < 64) {
    long e = (long)blockIdx.x * 64 + tid;
    int s = ldidx(eidx, e, i64);
    int d = ldidx(eidx, NE + e, i64);
    sdv[0][tid] = (unsigned)s; sdv[1][tid] = (unsigned)d;
    float rx = ldf(pos, 3 * (long)s, f32)     - ldf(pos, 3 * (long)d, f32);
    float ry = ldf(pos, 3 * (long)s + 1, f32) - ldf(pos, 3 * (long)d + 1, f32);
    float rz = ldf(pos, 3 * (long)s + 2, f32) - ldf(pos, 3 * (long)d + 2, f32);
    float dd = sqrtf(rx * rx + ry * ry + rz * rz + 1e-12f);
    float inv = 1.0f / dd;
    float ux = rx * inv, uy = ry * inv, uz = rz * inv;
    geom[tid][0] = ux; geom[tid][1] = uy; geom[tid][2] = uz;
    geom[tid][3] = ux * uy;
    geom[tid][4] = uy * uz;
    geom[tid][5] = (3.f * uz * uz - 1.f) * 0.28867513459481287f;  // /(2*sqrt(3))
    geom[tid][6] = ux * uz;
    geom[tid][7] = (ux * ux - uy * uy) * 0.5f;
    #pragma unroll
    for (int k = 0; k < 8; ++k) {
      float t = dd - (float)k * (5.0f / 7.0f);
      geom[tid][8 + k] = __expf(-t * t);
    }
  }
  __syncthreads();

  const int q = lane >> 4, colA = lane & 15;

  // --- h for this wave's 16 edges, straight into A-fragments ---
  short8 afrag0, afrag1;
  {
    const float* rb = &geom[wid * 16 + colA][8];
    #pragma unroll
    for (int i = 0; i < 8; ++i) {
      int k = q * 8 + i;
      float a = wr1s[512 + k];
      #pragma unroll
      for (int r = 0; r < 8; ++r) a += rb[r] * wr1s[r * 64 + k];
      afrag0[i] = (short)f2b(a / (1.f + __expf(-a)));
      int k2 = 32 + q * 8 + i;
      float a2 = wr1s[512 + k2];
      #pragma unroll
      for (int r = 0; r < 8; ++r) a2 += rb[r] * wr1s[r * 64 + k2];
      afrag1[i] = (short)f2b(a2 / (1.f + __expf(-a2)));
    }
  }

  // --- 28 MFMA: w for all 16 edges of this wave ---
  float4v acc[14];
  #pragma unroll
  for (int t = 0; t < 14; ++t) {
    int j = t * 16 + colA;
    short8 b0 = *(const short8*)&wr2t[j * 72 + q * 8];
    short8 b1 = *(const short8*)&wr2t[j * 72 + 32 + q * 8];
    float4v c = {0.f, 0.f, 0.f, 0.f};
    c = __builtin_amdgcn_mfma_f32_16x16x32_bf16(afrag0, b0, c, 0, 0, 0);
    c = __builtin_amdgcn_mfma_f32_16x16x32_bf16(afrag1, b1, c, 0, 0, 0);
    acc[t] = c;
  }

  // --- prefetch edge 0's source row ---
  {
    unsigned s0 = sdv[0][wid * 16];
    if (lane < 36) {
      uint4 u = ((const uint4*)(si1 + (size_t)s0 * DIMX))[lane];
      float* xp = &xsv[wid][0][lane * 8];
      xp[0] = b2f((unsigned short)(u.x & 0xffffu)); xp[1] = b2f((unsigned short)(u.x >> 16));
      xp[2] = b2f((unsigned short)(u.y & 0xffffu)); xp[3] = b2f((unsigned short)(u.y >> 16));
      xp[4] = b2f((unsigned short)(u.z & 0xffffu)); xp[5] = b2f((unsigned short)(u.z >> 16));
      xp[6] = b2f((unsigned short)(u.w & 0xffffu)); xp[7] = b2f((unsigned short)(u.w >> 16));
    }
  }
  asm volatile("" ::: "memory");

  #pragma unroll 1
  for (int g = 0; g < 4; ++g) {
    #pragma unroll
    for (int reg = 0; reg < 4; ++reg) {
      const int el = g * 4 + reg;
      const int eb = wid * 16 + el;
      const int cur = el & 1;
      // issue prefetch of next edge's source row
      uint4 pf;
      if (el < 15 && lane < 36) {
        unsigned sn = sdv[0][eb + 1];
        pf = ((const uint4*)(si1 + (size_t)sn * DIMX))[lane];
      }
      // unload this edge's w from C-regs (holder quad g, compile-time reg)
      if (q == g) {
        #pragma unroll
        for (int t = 0; t < 14; ++t) wev[wid][t * 16 + colA] = acc[t][reg] * 0.25f;
      }
      asm volatile("" ::: "memory");
      // messages + atomic scatter
      {
        unsigned dn = sdv[1][eb];
        float* cv = conv + (size_t)dn * DIMX;
        const float* G = geom[eb];
        float y1x = G[0], y1y = G[1], y1z = G[2];
        float y20 = G[3], y21 = G[4], y22 = G[5], y23 = G[6], y24 = G[7];
        const float* X = xsv[wid][cur];
        const float* W = wev[wid];
        #pragma unroll
        for (int r = 0; r < 5; ++r) {
          int j = r * 64 + lane;
          if (j < DIMX) {
            float val;
            if (j < 32) {
              int m = j;
              float d1 = X[32 + 3 * m] * y1x + X[33 + 3 * m] * y1y + X[34 + 3 * m] * y1z;
              float d2 = X[128 + 5 * m] * y20 + X[129 + 5 * m] * y21 + X[130 + 5 * m] * y22
                       + X[131 + 5 * m] * y23 + X[132 + 5 * m] * y24;
              val = W[m] * X[m] + W[128 + m] * d1 + W[192 + m] * d2;
            } else if (j < 128) {
              unsigned jj = j - 32; int m = jj / 3u, c = jj % 3u;
              float Yc = (c == 0) ? y1x : ((c == 1) ? y1y : y1z);
              val = W[32 + m] * X[j] + W[96 + m] * X[m] * Yc;
            } else {
              unsigned jj = j - 128; int m = jj / 5u, c = jj % 5u;
              float Yc = (c == 0) ? y20 : (c == 1) ? y21 : (c == 2) ? y22 : (c == 3) ? y23 : y24;
              val = W[64 + m] * X[j] + W[160 + m] * X[m] * Yc;
            }
            atomicAdd(cv + j, val);   // norm already folded into wev
          }
        }
      }
      // store prefetched row into the other buffer
      if (el < 15 && lane < 36) {
        float* xp = &xsv[wid][cur ^ 1][lane * 8];
        xp[0] = b2f((unsigned short)(pf.x & 0xffffu)); xp[1] = b2f((unsigned short)(pf.x >> 16));
        xp[2] = b2f((unsigned short)(pf.y & 0xffffu)); xp[3] = b2f((unsigned short)(pf.y >> 16));
        xp[4] = b2f((unsigned short)(pf.z & 0xffffu)); xp[5] = b2f((unsigned short)(pf.z >> 16));
        xp[6] = b2f((unsigned short)(pf.w & 0xffffu)); xp[7] = b2f((unsigned short)(pf.w >> 16));
      }
      asm volatile("" ::: "memory");
    }
  }
}

// ---------------- Kernel 4: si2 = linear(conv); mixed = nodes + si2; gate -> fp32 out ----------------
__global__ __launch_bounds__(256) void k_gate(
    const float* __restrict__ conv,
    const void* __restrict__ nodes,
    const void* __restrict__ W0,
    const void* __restrict__ W1,
    const void* __restrict__ W2,
    const void* __restrict__ Wg,
    float* __restrict__ out,
    const int* __restrict__ flags) {
  const int f32 = flags[0];
  __shared__ float Ws[3072];
  __shared__ float Wgs[2048];   // Wg [32][64]
  __shared__ float xs[4 * DIMX];
  __shared__ float m0s[4][33];
  __shared__ float gs[4][65];
  int tid = threadIdx.x;
  for (int idx = tid; idx < 3072; idx += 256) {
    int l = idx >> 10, rem = idx & 1023;
    const void* w = (l == 0) ? W0 : ((l == 1) ? W1 : W2);
    Ws[idx] = ldf(w, rem, f32);
  }
  for (int idx = tid; idx < 2048; idx += 256) Wgs[idx] = ldf(Wg, idx, f32);
  long base = (long)blockIdx.x * 4;
  for (int idx = tid; idx < 1152; idx += 256) xs[idx] = conv[base * DIMX + idx];
  __syncthreads();
  int wid = tid >> 6, lane = tid & 63;
  long node = base + wid;
  const float* x = xs + wid * DIMX;
  float mixed[5];
  #pragma unroll
  for (int r = 0; r < 5; ++r) {
    int j = r * 64 + lane;
    if (j < DIMX) {
      float acc = 0.f;
      if (j < 32) {
        #pragma unroll
        for (int i = 0; i < 32; ++i) acc += x[i] * Ws[i * 32 + j];
      } else if (j < 128) {
        unsigned jj = j - 32; int m = jj / 3u, c = jj % 3u;
        #pragma unroll
        for (int i = 0; i < 32; ++i) acc += x[32 + 3 * i + c] * Ws[1024 + i * 32 + m];
      } else {
        unsigned jj = j - 128; int m = jj / 5u, c = jj % 5u;
        #pragma unroll
        for (int i = 0; i < 32; ++i) acc += x[128 + 5 * i + c] * Ws[2048 + i * 32 + m];
      }
      acc += ldf(nodes, node * DIMX + j, f32);
      mixed[r] = acc;
      if (j < 32) m0s[wid][j] = acc;
    }
  }
  __syncthreads();
  {
    float ga = 0.f;
    #pragma unroll
    for (int m = 0; m < 32; ++m) ga += m0s[wid][m] * Wgs[m * 64 + lane];
    gs[wid][lane] = 1.f / (1.f + __expf(-ga));
  }
  __syncthreads();
  #pragma unroll
  for (int r = 0; r < 5; ++r) {
    int j = r * 64 + lane;
    if (j < DIMX) {
      float v = mixed[r];
      float o;
      if (j < 32) {
        o = v / (1.f + __expf(-v));                       // silu
      } else if (j < 128) {
        int m = (unsigned)(j - 32) / 3u; o = v * gs[wid][m];
      } else {
        int m = (unsigned)(j - 128) / 5u; o = v * gs[wid][32 + m];
      }
      out[node * DIMX + j] = o;
    }
  }
}

extern "C" void kernel_launch(void* const* d_in, const int* in_sizes, int n_in,
                              void* d_out, int out_size, void* d_ws, size_t ws_size,
                              hipStream_t stream) {
  const void* nodes = d_in[0];
  const void* pos   = d_in[1];
  const void* W0    = d_in[2];
  const void* W1    = d_in[3];
  const void* W2    = d_in[4];
  const void* Wr1   = d_in[5];
  const void* br1   = d_in[6];
  const void* Wr2   = d_in[7];
  const void* Wg    = d_in[8];
  const int* eidx   = (const int*)d_in[10];

  int* flags = (int*)d_ws;                                            // 256 B header
  unsigned short* si1 = (unsigned short*)((char*)d_ws + 256);         // 28.8 MB bf16
  float* conv = (float*)((char*)d_ws + 256 + (size_t)NN * DIMX * 2);  // 57.6 MB fp32
  float* out = (float*)d_out;

  hipLaunchKernelGGL(k_detect, dim3(1), dim3(64), 0, stream,
                     (const unsigned short*)pos, eidx, flags);
  hipLaunchKernelGGL(k_linear1, dim3(NN / 4), dim3(256), 0, stream,
                     nodes, W0, W1, W2, si1, flags);
  hipLaunchKernelGGL(k_zero, dim3((NN * DIMX / 4 + 255) / 256), dim3(256), 0, stream, conv);
  hipLaunchKernelGGL(k_edges, dim3(NE / 64), dim3(256), 0, stream,
                     pos, eidx, Wr1, br1, Wr2, si1, conv, flags);
  hipLaunchKernelGGL(k_gate, dim3(NN / 4), dim3(256), 0, stream,
                     conv, nodes, W0, W1, W2, Wg, out, flags);
}

// Round 6
// 1206.482 us; speedup vs baseline: 1.4464x; 1.0858x over previous
//
#include <hip/hip_runtime.h>
#include <hip/hip_bf16.h>

#define NN 50000
#define NE 800000
#define DIMX 288
#define NPB 16   // nodes per block in k_linear1 / k_gate

typedef float float4v __attribute__((ext_vector_type(4)));
typedef short short8 __attribute__((ext_vector_type(8)));

__device__ __forceinline__ float b2f(unsigned short u) {
  return __uint_as_float(((unsigned int)u) << 16);
}
__device__ __forceinline__ unsigned short f2b(float f) {
  unsigned int x = __float_as_uint(f);
  x += 0x7fffu + ((x >> 16) & 1u);
  return (unsigned short)(x >> 16);
}
__device__ __forceinline__ float ldf(const void* p, long i, int f32) {
  return f32 ? ((const float*)p)[i] : b2f(((const unsigned short*)p)[i]);
}
__device__ __forceinline__ int ldidx(const int* p, long i, int i64) {
  return i64 ? p[2 * i] : p[i];
}

// ---------------- Kernel 0: dtype detector ----------------
__global__ void k_detect(const unsigned short* __restrict__ pos_u16,
                         const int* __restrict__ eidx_i32,
                         int* __restrict__ flags) {
  if (threadIdx.x == 0 && blockIdx.x == 0) {
    int insane = 0;
    for (int i = 0; i < 128; ++i) {
      unsigned short u = pos_u16[i];
      int e = (u >> 7) & 0xff;
      if (e >= 0xC2) insane++;          // |x| >= 2^67 impossible for bf16 pos in [0,10]
    }
    flags[0] = (insane >= 2) ? 1 : 0;
    int nz = 0;
    for (int i = 1; i < 16; i += 2) nz += (eidx_i32[i] != 0);
    flags[1] = (nz == 0) ? 1 : 0;       // int64 high words all zero
  }
}

// ---------------- Kernel 1: si1 = irreps_linear(nodes) -> bf16 ----------------
// 16 nodes/block (4 per wave) to amortize weight staging.
__global__ __launch_bounds__(256) void k_linear1(
    const void* __restrict__ nodes,
    const void* __restrict__ W0,
    const void* __restrict__ W1,
    const void* __restrict__ W2,
    unsigned short* __restrict__ si1,
    const int* __restrict__ flags) {
  const int f32 = flags[0];
  __shared__ float Ws[3072];
  __shared__ float xs[NPB * DIMX];
  int tid = threadIdx.x;
  for (int idx = tid; idx < 3072; idx += 256) {
    int l = idx >> 10, rem = idx & 1023;
    const void* w = (l == 0) ? W0 : ((l == 1) ? W1 : W2);
    Ws[idx] = ldf(w, rem, f32);
  }
  long base = (long)blockIdx.x * NPB;
  for (int idx = tid; idx < NPB * DIMX; idx += 256)
    xs[idx] = ldf(nodes, base * DIMX + idx, f32);
  __syncthreads();
  int wid = tid >> 6, lane = tid & 63;
  #pragma unroll 1
  for (int t = 0; t < 4; ++t) {
    int nl = wid * 4 + t;
    long node = base + nl;
    const float* x = xs + nl * DIMX;
    #pragma unroll
    for (int r = 0; r < 5; ++r) {
      int j = r * 64 + lane;
      if (j < DIMX) {
        float acc = 0.f;
        if (j < 32) {
          #pragma unroll
          for (int i = 0; i < 32; ++i) acc += x[i] * Ws[i * 32 + j];
        } else if (j < 128) {
          unsigned jj = j - 32; int m = jj / 3u, c = jj % 3u;
          #pragma unroll
          for (int i = 0; i < 32; ++i) acc += x[32 + 3 * i + c] * Ws[1024 + i * 32 + m];
        } else {
          unsigned jj = j - 128; int m = jj / 5u, c = jj % 5u;
          #pragma unroll
          for (int i = 0; i < 32; ++i) acc += x[128 + 5 * i + c] * Ws[2048 + i * 32 + m];
        }
        si1[node * DIMX + j] = f2b(acc);
      }
    }
  }
}

// ---------------- Kernel 2: zero the conv accumulator ----------------
__global__ __launch_bounds__(256) void k_zero(float* __restrict__ conv) {
  long idx = (long)blockIdx.x * 256 + threadIdx.x;
  if (idx < (long)NN * DIMX / 4) {
    float4 z; z.x = 0.f; z.y = 0.f; z.z = 0.f; z.w = 0.f;
    ((float4*)conv)[idx] = z;
  }
}

// ---------------- Kernel 3: fused edge kernel ----------------
// Phase A: stage Wr2^T in ov; geometry; h (0.25 folded) -> A-frags; 28 MFMA.
// Barrier. Phase B: ov reused as per-wave bf16 row cache; each wave batch-
// gathers its 16 source rows (8 loads in flight), then per edge: unload w
// from C-regs to wev, compute messages from LDS, atomicAdd scatter.
__global__ __launch_bounds__(256) void k_edges(
    const void* __restrict__ pos,
    const int* __restrict__ eidx,
    const void* __restrict__ Wr1,
    const void* __restrict__ br1,
    const void* __restrict__ Wr2,
    const unsigned short* __restrict__ si1,
    float* __restrict__ conv,
    const int* __restrict__ flags) {
  const int f32 = flags[0];
  const int i64 = flags[1];
  __shared__ unsigned short ov[18944];  // phase A: wr2t[j*72+k] (16128); phase B: xrows[row*296+i] (18944)
  __shared__ float wr1s[576];           // Wr1 [8][64] + br1 [64]
  __shared__ float geom[64][16];        // Y1(3) Y2(5) rbf(8)
  __shared__ unsigned int sdv[2][64];   // src, dst
  __shared__ float wev[4][228];         // per-wave current-edge w (norm folded)
  int tid = threadIdx.x, lane = tid & 63, wid = tid >> 6;

  for (int idx = tid; idx < 512; idx += 256) wr1s[idx] = ldf(Wr1, idx, f32);
  if (tid < 64) wr1s[512 + tid] = ldf(br1, tid, f32);
  for (int idx = tid; idx < 64 * 224; idx += 256) {   // global-coalesced, transpose into LDS
    int k = idx / 224, j = idx - k * 224;
    ov[j * 72 + k] = f2b(ldf(Wr2, idx, f32));
  }
  if (tid < 64) {
    long e = (long)blockIdx.x * 64 + tid;
    int s = ldidx(eidx, e, i64);
    int d = ldidx(eidx, NE + e, i64);
    sdv[0][tid] = (unsigned)s; sdv[1][tid] = (unsigned)d;
    float rx = ldf(pos, 3 * (long)s, f32)     - ldf(pos, 3 * (long)d, f32);
    float ry = ldf(pos, 3 * (long)s + 1, f32) - ldf(pos, 3 * (long)d + 1, f32);
    float rz = ldf(pos, 3 * (long)s + 2, f32) - ldf(pos, 3 * (long)d + 2, f32);
    float dd = sqrtf(rx * rx + ry * ry + rz * rz + 1e-12f);
    float inv = 1.0f / dd;
    float ux = rx * inv, uy = ry * inv, uz = rz * inv;
    geom[tid][0] = ux; geom[tid][1] = uy; geom[tid][2] = uz;
    geom[tid][3] = ux * uy;
    geom[tid][4] = uy * uz;
    geom[tid][5] = (3.f * uz * uz - 1.f) * 0.28867513459481287f;
    geom[tid][6] = ux * uz;
    geom[tid][7] = (ux * ux - uy * uy) * 0.5f;
    #pragma unroll
    for (int k = 0; k < 8; ++k) {
      float t = dd - (float)k * (5.0f / 7.0f);
      geom[tid][8 + k] = __expf(-t * t);
    }
  }
  __syncthreads();

  const int q = lane >> 4, colA = lane & 15;
  const int myrow0 = wid * 16;

  // --- h (scaled by 0.25 = 1/sqrt(AVG_DEG), exact pow2) into A-fragments ---
  short8 afrag0, afrag1;
  {
    const float* rb = &geom[myrow0 + colA][8];
    #pragma unroll
    for (int i = 0; i < 8; ++i) {
      int k = q * 8 + i;
      float a = wr1s[512 + k];
      #pragma unroll
      for (int r = 0; r < 8; ++r) a += rb[r] * wr1s[r * 64 + k];
      afrag0[i] = (short)f2b(0.25f * a / (1.f + __expf(-a)));
      int k2 = 32 + q * 8 + i;
      float a2 = wr1s[512 + k2];
      #pragma unroll
      for (int r = 0; r < 8; ++r) a2 += rb[r] * wr1s[r * 64 + k2];
      afrag1[i] = (short)f2b(0.25f * a2 / (1.f + __expf(-a2)));
    }
  }

  // --- 28 MFMA: w for all 16 edges of this wave ---
  float4v acc[14];
  #pragma unroll
  for (int t = 0; t < 14; ++t) {
    int j = t * 16 + colA;
    short8 b0 = *(const short8*)&ov[j * 72 + q * 8];
    short8 b1 = *(const short8*)&ov[j * 72 + 32 + q * 8];
    float4v c = {0.f, 0.f, 0.f, 0.f};
    c = __builtin_amdgcn_mfma_f32_16x16x32_bf16(afrag0, b0, c, 0, 0, 0);
    c = __builtin_amdgcn_mfma_f32_16x16x32_bf16(afrag1, b1, c, 0, 0, 0);
    acc[t] = c;
  }

  __syncthreads();   // all waves done reading wr2t; ov becomes row cache

  // --- batch-gather this wave's 16 source rows (bf16, raw copy, b128 I/O) ---
  if (lane < 36) {
    #pragma unroll
    for (int b = 0; b < 2; ++b) {
      uint4 t[8];
      #pragma unroll
      for (int e = 0; e < 8; ++e) {
        unsigned s = sdv[0][myrow0 + b * 8 + e];
        t[e] = ((const uint4*)(si1 + (size_t)s * DIMX))[lane];
      }
      #pragma unroll
      for (int e = 0; e < 8; ++e) {
        ((uint4*)&ov[(size_t)(myrow0 + b * 8 + e) * 296])[lane] = t[e];
      }
    }
  }
  asm volatile("" ::: "memory");

  #pragma unroll 1
  for (int g = 0; g < 4; ++g) {
    #pragma unroll
    for (int reg = 0; reg < 4; ++reg) {
      const int el = g * 4 + reg;
      const int eb = myrow0 + el;
      if (q == g) {
        #pragma unroll
        for (int t = 0; t < 14; ++t) wev[wid][t * 16 + colA] = acc[t][reg];
      }
      asm volatile("" ::: "memory");
      {
        unsigned dn = sdv[1][eb];
        float* cv = conv + (size_t)dn * DIMX;
        const float* G = geom[eb];
        float y1x = G[0], y1y = G[1], y1z = G[2];
        float y20 = G[3], y21 = G[4], y22 = G[5], y23 = G[6], y24 = G[7];
        const unsigned short* X = &ov[(size_t)eb * 296];
        const float* W = wev[wid];
        #pragma unroll
        for (int r = 0; r < 5; ++r) {
          int j = r * 64 + lane;
          if (j < DIMX) {
            float val;
            if (j < 32) {
              int m = j;
              float d1 = b2f(X[32 + 3 * m]) * y1x + b2f(X[33 + 3 * m]) * y1y + b2f(X[34 + 3 * m]) * y1z;
              float d2 = b2f(X[128 + 5 * m]) * y20 + b2f(X[129 + 5 * m]) * y21 + b2f(X[130 + 5 * m]) * y22
                       + b2f(X[131 + 5 * m]) * y23 + b2f(X[132 + 5 * m]) * y24;
              val = W[m] * b2f(X[m]) + W[128 + m] * d1 + W[192 + m] * d2;
            } else if (j < 128) {
              unsigned jj = j - 32; int m = jj / 3u, c = jj % 3u;
              float Yc = (c == 0) ? y1x : ((c == 1) ? y1y : y1z);
              val = W[32 + m] * b2f(X[j]) + W[96 + m] * b2f(X[m]) * Yc;
            } else {
              unsigned jj = j - 128; int m = jj / 5u, c = jj % 5u;
              float Yc = (c == 0) ? y20 : (c == 1) ? y21 : (c == 2) ? y22 : (c == 3) ? y23 : y24;
              val = W[64 + m] * b2f(X[j]) + W[160 + m] * b2f(X[m]) * Yc;
            }
            atomicAdd(cv + j, val);
          }
        }
      }
      asm volatile("" ::: "memory");
    }
  }
}

// ---------------- Kernel 4: si2 = linear(conv); mixed = nodes + si2; gate -> fp32 ----------------
// 16 nodes/block; gate state is per-node & same-wave -> no block barriers in loop.
__global__ __launch_bounds__(256) void k_gate(
    const float* __restrict__ conv,
    const void* __restrict__ nodes,
    const void* __restrict__ W0,
    const void* __restrict__ W1,
    const void* __restrict__ W2,
    const void* __restrict__ Wg,
    float* __restrict__ out,
    const int* __restrict__ flags) {
  const int f32 = flags[0];
  __shared__ float Ws[3072];
  __shared__ float Wgs[2048];
  __shared__ float xs[NPB * DIMX];
  __shared__ float m0s[NPB][33];
  __shared__ float gs[NPB][65];
  int tid = threadIdx.x;
  for (int idx = tid; idx < 3072; idx += 256) {
    int l = idx >> 10, rem = idx & 1023;
    const void* w = (l == 0) ? W0 : ((l == 1) ? W1 : W2);
    Ws[idx] = ldf(w, rem, f32);
  }
  for (int idx = tid; idx < 2048; idx += 256) Wgs[idx] = ldf(Wg, idx, f32);
  long base = (long)blockIdx.x * NPB;
  for (int idx = tid; idx < NPB * DIMX; idx += 256) xs[idx] = conv[base * DIMX + idx];
  __syncthreads();
  int wid = tid >> 6, lane = tid & 63;
  #pragma unroll 1
  for (int t = 0; t < 4; ++t) {
    int nl = wid * 4 + t;
    long node = base + nl;
    const float* x = xs + nl * DIMX;
    float mixed[5];
    #pragma unroll
    for (int r = 0; r < 5; ++r) {
      int j = r * 64 + lane;
      if (j < DIMX) {
        float acc = 0.f;
        if (j < 32) {
          #pragma unroll
          for (int i = 0; i < 32; ++i) acc += x[i] * Ws[i * 32 + j];
        } else if (j < 128) {
          unsigned jj = j - 32; int m = jj / 3u, c = jj % 3u;
          #pragma unroll
          for (int i = 0; i < 32; ++i) acc += x[32 + 3 * i + c] * Ws[1024 + i * 32 + m];
        } else {
          unsigned jj = j - 128; int m = jj / 5u, c = jj % 5u;
          #pragma unroll
          for (int i = 0; i < 32; ++i) acc += x[128 + 5 * i + c] * Ws[2048 + i * 32 + m];
        }
        acc += ldf(nodes, node * DIMX + j, f32);
        mixed[r] = acc;
        if (j < 32) m0s[nl][j] = acc;
      }
    }
    asm volatile("" ::: "memory");
    {
      float ga = 0.f;
      #pragma unroll
      for (int m = 0; m < 32; ++m) ga += m0s[nl][m] * Wgs[m * 64 + lane];
      gs[nl][lane] = 1.f / (1.f + __expf(-ga));
    }
    asm volatile("" ::: "memory");
    #pragma unroll
    for (int r = 0; r < 5; ++r) {
      int j = r * 64 + lane;
      if (j < DIMX) {
        float v = mixed[r];
        float o;
        if (j < 32) {
          o = v / (1.f + __expf(-v));
        } else if (j < 128) {
          int m = (unsigned)(j - 32) / 3u; o = v * gs[nl][m];
        } else {
          int m = (unsigned)(j - 128) / 5u; o = v * gs[nl][32 + m];
        }
        out[node * DIMX + j] = o;
      }
    }
  }
}

extern "C" void kernel_launch(void* const* d_in, const int* in_sizes, int n_in,
                              void* d_out, int out_size, void* d_ws, size_t ws_size,
                              hipStream_t stream) {
  const void* nodes = d_in[0];
  const void* pos   = d_in[1];
  const void* W0    = d_in[2];
  const void* W1    = d_in[3];
  const void* W2    = d_in[4];
  const void* Wr1   = d_in[5];
  const void* br1   = d_in[6];
  const void* Wr2   = d_in[7];
  const void* Wg    = d_in[8];
  const int* eidx   = (const int*)d_in[10];

  int* flags = (int*)d_ws;
  unsigned short* si1 = (unsigned short*)((char*)d_ws + 256);
  float* conv = (float*)((char*)d_ws + 256 + (size_t)NN * DIMX * 2);
  float* out = (float*)d_out;

  hipLaunchKernelGGL(k_detect, dim3(1), dim3(64), 0, stream,
                     (const unsigned short*)pos, eidx, flags);
  hipLaunchKernelGGL(k_linear1, dim3(NN / NPB), dim3(256), 0, stream,
                     nodes, W0, W1, W2, si1, flags);
  hipLaunchKernelGGL(k_zero, dim3((NN * DIMX / 4 + 255) / 256), dim3(256), 0, stream, conv);
  hipLaunchKernelGGL(k_edges, dim3(NE / 64), dim3(256), 0, stream,
                     pos, eidx, Wr1, br1, Wr2, si1, conv, flags);
  hipLaunchKernelGGL(k_gate, dim3(NN / NPB), dim3(256), 0, stream,
                     conv, nodes, W0, W1, W2, Wg, out, flags);
}